// Round 12
// baseline (267.495 us; speedup 1.0000x reference)
//
#include <hip/hip_runtime.h>
#include <stdint.h>

// ModulatedConv2d: B=8, C=512, O=512, K=3, WDIM=512, H=W=64
// Round-16: T4 (counted vmcnt) on R11's harness-verified flat-K structure.
//   R11's __syncthreads drained vmcnt(0) at every barrier -> guide m218's
//   "drain0 == 1-phase" null. Replace with raw s_barrier + counted waits:
//   wait N = loads of the next in-flight stage (A-stage=4, A+B-stage=9 per
//   wave, made exec-uniform by redistributing the B remainder 1 instr/wave).
//   All addressing/staging/MFMA/epilogue code verbatim from R11 (verified).

#define MOD_SCALE  0.044194173824159216f   // 1/sqrt(512)
#define CONV_SCALE 0.014731391274719739f   // 1/sqrt(4608)

typedef __attribute__((ext_vector_type(4))) float f32x4;
typedef __attribute__((ext_vector_type(8))) short bf16x8;

__device__ inline unsigned short f2bf(float f) {   // round-to-nearest-even
  uint32_t u = __float_as_uint(f);
  uint32_t r = (u + 0x7fffu + ((u >> 16) & 1u)) >> 16;
  return (unsigned short)r;
}

__device__ inline void gload_lds16(const void* g, void* l) {
  __builtin_amdgcn_global_load_lds(
      (const __attribute__((address_space(1))) void*)g,
      (__attribute__((address_space(3))) void*)l, 16, 0, 0);
}

// ---------- style: s[b][c] = w[b].modw[c]*MOD_SCALE + modb[c] + 1 ----------
__global__ __launch_bounds__(256) void k_style(const float* __restrict__ w,
                                               const float* __restrict__ modw,
                                               const float* __restrict__ modb,
                                               float* __restrict__ s_out) {
  __shared__ float red[256];
  const int tid = threadIdx.x;
  const int sb = blockIdx.x;
  const int cb = sb & 7, b = sb >> 3;
  const int cl = tid >> 2, qq = tid & 3;
  const int c = (cb << 6) + cl;
  const float4* wd = (const float4*)(w + (b << 9) + (qq << 7));
  const float4* md = (const float4*)(modw + ((size_t)c << 9) + (qq << 7));
  float acc = 0.f;
#pragma unroll
  for (int i = 0; i < 32; ++i) {
    float4 a = wd[i], m = md[i];
    acc += a.x * m.x + a.y * m.y + a.z * m.z + a.w * m.w;
  }
  red[tid] = acc;
  __syncthreads();
  if (tid < 64) {
    float v = red[tid * 4] + red[tid * 4 + 1] + red[tid * 4 + 2] + red[tid * 4 + 3];
    int cc = (cb << 6) + tid;
    s_out[(b << 9) + cc] = v * MOD_SCALE + modb[cc] + 1.0f;
  }
}

// ---------- merged mid-stage: fwd (blk<512) | xpose (<1024) | border (<3104) ----
__global__ __launch_bounds__(256) void k_mid(const float* __restrict__ bw,
                                             const float* __restrict__ s,
                                             unsigned short* __restrict__ awT,
                                             float* __restrict__ d_out,
                                             const float* __restrict__ x,
                                             unsigned short* __restrict__ xp) {
  __shared__ uint32_t tb[64 * 260];   // 66,560 B (fwd branch reuses as floats)
  const int blk = blockIdx.x;
  const int tid = threadIdx.x;

  if (blk < 512) {
    // ---------------- fwd: one block per o ----------------
    float* lw  = (float*)tb;          // 4608 floats
    float* ls  = lw + 4608;           // 4096 floats
    float* red = ls + 4096;           // 32 floats
    const int o = blk;
    {
      const float4* src = (const float4*)(bw + (size_t)o * 4608);
      float4* dst = (float4*)lw;
#pragma unroll
      for (int i = 0; i < 4; ++i) dst[tid + (i << 8)] = src[tid + (i << 8)];
      if (tid < 128) dst[tid + 1024] = src[tid + 1024];
    }
    {
      const float4* src = (const float4*)s;
      float4* dst = (float4*)ls;
#pragma unroll
      for (int i = 0; i < 4; ++i) dst[tid + (i << 8)] = src[tid + (i << 8)];
    }
    __syncthreads();
    const int c0 = tid << 1;
    const int base = c0 * 9;
    float wq0 = 0.f, wq1 = 0.f;
#pragma unroll
    for (int j = 0; j < 9; ++j) {
      float a = lw[base + j];      wq0 += a * a;
      float b2 = lw[base + 9 + j]; wq1 += b2 * b2;
    }
    const int lane = tid & 63, wv = tid >> 6;
#pragma unroll
    for (int b = 0; b < 8; ++b) {
      float s0 = ls[(b << 9) + c0], s1 = ls[(b << 9) + c0 + 1];
      float v = wq0 * s0 * s0 + wq1 * s1 * s1;
#pragma unroll
      for (int off = 32; off > 0; off >>= 1) v += __shfl_down(v, off, 64);
      if (lane == 0) red[(b << 2) + wv] = v;
    }
    __syncthreads();
    if (tid < 8) {
      float a = red[tid << 2] + red[(tid << 2) + 1] + red[(tid << 2) + 2] + red[(tid << 2) + 3];
      d_out[(tid << 9) + o] = rsqrtf(a * (1.0f / 4608.0f)) * CONV_SCALE;
    }
    uint32_t* dst = (uint32_t*)(awT + (size_t)o * 4608);
#pragma unroll
    for (int j = 0; j < 9; ++j)
      dst[(j << 8) + tid] = (uint32_t)f2bf(lw[base + j]) |
                            ((uint32_t)f2bf(lw[base + 9 + j]) << 16);
  } else if (blk < 1024) {
    // ---------------- xpose: one block per (b, y) ----------------
    const int q = blk - 512;
    const int b = q >> 6, y = q & 63;
    const int px4 = tid & 15;
    const int cp  = tid >> 4;
    const float* xb = x + (size_t)(b << 9) * 4096 + (y << 6) + (px4 << 2);
    const float* sb = s + (b << 9);
#pragma unroll
    for (int it = 0; it < 16; ++it) {
      const int cpair = cp + (it << 4);
      const int c0 = cpair << 1;
      const float4 a0 = *(const float4*)(xb + (size_t)c0 * 4096);
      const float4 a1 = *(const float4*)(xb + (size_t)(c0 + 1) * 4096);
      const float s0 = sb[c0], s1 = sb[c0 + 1];
      const int pxb = px4 << 2;
      tb[(pxb + 0) * 260 + cpair] = (uint32_t)f2bf(a0.x * s0) | ((uint32_t)f2bf(a1.x * s1) << 16);
      tb[(pxb + 1) * 260 + cpair] = (uint32_t)f2bf(a0.y * s0) | ((uint32_t)f2bf(a1.y * s1) << 16);
      tb[(pxb + 2) * 260 + cpair] = (uint32_t)f2bf(a0.z * s0) | ((uint32_t)f2bf(a1.z * s1) << 16);
      tb[(pxb + 3) * 260 + cpair] = (uint32_t)f2bf(a0.w * s0) | ((uint32_t)f2bf(a1.w * s1) << 16);
    }
    __syncthreads();
    const int wv = tid >> 6, l = tid & 63;
    uint32_t* xpw = (uint32_t*)xp;
#pragma unroll
    for (int it = 0; it < 16; ++it) {
      const int px = (wv << 4) + it;
      const uint4 v = *(const uint4*)(tb + px * 260 + (l << 2));
      const size_t base = ((size_t)b * 4356 + (size_t)(y + 1) * 66 + (px + 1)) << 8;
      ((uint4*)(xpw + base))[l] = v;
    }
  } else {
    // ---------------- border: zero the 1-px frame ----------------
    const int q = blk - 1024;
    const int b = q / 260, p = q - b * 260;
    int py, px;
    if (p < 66)       { py = 0;       px = p; }
    else if (p < 132) { py = 65;      px = p - 66; }
    else if (p < 196) { py = p - 131; px = 0; }
    else              { py = p - 195; px = 65; }
    uint32_t* dst = (uint32_t*)(xp + ((size_t)b * 4356 + py * 66 + px) * 512);
    dst[tid] = 0u;
  }
}

// ---------- main conv: 256x256 block, 512 thr, flat-K 72 steps, counted vmcnt ----
// LDS: As[2] 2x32 KB + Bs[2] 2x33 KB = 130 KB. Per step: counted s_waitcnt
// (N = loads of next in-flight stage) -> s_barrier -> 64 MFMA/wave ->
// s_barrier -> issue stage(it+2). Per-wave uniform counts: A=4, A+B=9.
__global__ __launch_bounds__(512, 1) void k_conv(const unsigned short* __restrict__ awT,
                                                 const unsigned short* __restrict__ xpad,
                                                 const float* __restrict__ dmod,
                                                 float* __restrict__ out) {
  __shared__ alignas(16) unsigned short As[2][16384];  // 2 x 32 KB
  __shared__ alignas(16) unsigned short Bs[2][16896];  // 2 x 33 KB
  const int tid = threadIdx.x;

  const int nI = blockIdx.x;           // 0..15
  const int m0 = blockIdx.y << 8;      // 0 or 256
  const int b  = blockIdx.z;
  const int n0 = nI << 8;
  const int y0 = nI << 2;              // 4 output rows per tile

  const int srow = tid >> 3;                         // 0..63
  const int schk = ((tid & 7) - (srow & 7)) & 7;     // logical chunk to fetch
  const int scol = schk << 3;

  const unsigned short* A0 = awT + (size_t)(m0 + srow) * 4608 + scol;
  const size_t bx = (size_t)b * (66 * 66 * 512);
  const unsigned short* B0 = xpad + bx + (size_t)(y0 * 66 + srow) * 512 + scol;

  const int lane = tid & 63;
  const int wv   = tid >> 6;           // 0..7
  const int moff = (wv >> 1) << 6;     // 0,64,128,192
  const int lm   = lane & 15;
  const int g4   = lane >> 4;

  const int arow = moff + lm;
  int aoff[2];
#pragma unroll
  for (int h = 0; h < 2; ++h)
    aoff[h] = arow * 64 + ((((h << 2) + g4) + arow) & 7) * 8;
  int boff[3][2][2];   // [kx][jr][h]
#pragma unroll
  for (int kx = 0; kx < 3; ++kx)
#pragma unroll
    for (int jr = 0; jr < 2; ++jr) {
      const int rb = ((wv & 1) * 2 + jr) * 66 + lm + kx;
#pragma unroll
      for (int h = 0; h < 2; ++h)
        boff[kx][jr][h] = rb * 64 + ((((h << 2) + g4) + rb) & 7) * 8;
    }

  f32x4 acc[4][8];
#pragma unroll
  for (int i = 0; i < 4; ++i)
#pragma unroll
    for (int j = 0; j < 8; ++j) acc[i][j] = (f32x4){0.f, 0.f, 0.f, 0.f};

  // stage one 32 KB A panel (tap (ky,kx), c-slice kb): 4 instr/wave
  auto stageA = [&](int buf, int ky, int kx, int kb) {
    const unsigned short* Ap = A0 + (((ky * 3 + kx) << 9) + (kb << 6));
#pragma unroll
    for (int g = 0; g < 4; ++g)
      gload_lds16(Ap + (size_t)(g << 6) * 4608, &As[buf][(g << 12) + (tid << 3)]);
  };
  // stage one 33 KB B strip: 4 + 1 (remainder, exec-uniform 1/wave) = 5 instr/wave
  auto stageB = [&](int buf, int ky, int kb) {
    const unsigned short* Bp = B0 + (size_t)(ky * 66) * 512 + (kb << 6);
#pragma unroll
    for (int g = 0; g < 4; ++g)
      gload_lds16(Bp + (size_t)(g << 6) * 512, &Bs[buf][(g << 12) + (tid << 3)]);
    if (lane < 8) {   // rows 256..263: seg = wv*8+lane, swizzle-consistent
      const int rchk = (lane - wv) & 7;
      const unsigned short* gp = xpad + bx +
          (size_t)((y0 + ky) * 66 + 256 + wv) * 512 + (rchk << 3) + (kb << 6);
      gload_lds16(gp, &Bs[buf][16384 + (wv << 6) + (lane << 3)]);
    }
  };
  // one step's MFMA: 64 per wave (R11-verified)
  auto mstep = [&](int ab, int bb, int kx) {
    __builtin_amdgcn_s_setprio(1);
#pragma unroll
    for (int h = 0; h < 2; ++h) {
      bf16x8 af[4], bfr[8];
      const unsigned short* pa = As[ab] + aoff[h];
#pragma unroll
      for (int i = 0; i < 4; ++i) af[i] = *(const bf16x8*)(pa + (i << 10));
#pragma unroll
      for (int j = 0; j < 8; ++j)
        bfr[j] = *(const bf16x8*)(Bs[bb] + boff[kx][j >> 2][h] + ((j & 3) << 10));
#pragma unroll
      for (int i = 0; i < 4; ++i)
#pragma unroll
        for (int j = 0; j < 8; ++j)
          acc[i][j] = __builtin_amdgcn_mfma_f32_16x16x32_bf16(af[i], bfr[j], acc[i][j], 0, 0, 0);
    }
    __builtin_amdgcn_s_setprio(0);
  };

  // prologue: S(0) = A(ky0,kx0,kb0)+B [9];  S(1) = A(ky0,kx1,kb0) [4]
  stageA(0, 0, 0, 0);
  stageB(0, 0, 0);
  stageA(1, 0, 1, 0);

  int ab = 0, bb = 0;
#pragma unroll 1
  for (int t = 0; t < 24; ++t) {
    const int ky = t >> 3, kb = t & 7;
    const int nky = (kb == 7) ? ky + 1 : ky;
    const int nkb = (kb == 7) ? 0 : kb + 1;
    // ---- step kx0: S(it+1)=A(kx1) in flight [4] ----
    asm volatile("s_waitcnt vmcnt(4)" ::: "memory");
    __builtin_amdgcn_sched_barrier(0);
    __builtin_amdgcn_s_barrier();
    mstep(ab, bb, 0);
    __builtin_amdgcn_s_barrier();
    stageA(ab, ky, 2, kb);                 // S(it+2) -> buf just read
    ab ^= 1;
    // ---- step kx1: S(it+1)=A(kx2) in flight [4] ----
    asm volatile("s_waitcnt vmcnt(4)" ::: "memory");
    __builtin_amdgcn_sched_barrier(0);
    __builtin_amdgcn_s_barrier();
    mstep(ab, bb, 1);
    __builtin_amdgcn_s_barrier();
    if (t < 23) { stageA(ab, nky, 0, nkb); stageB(bb ^ 1, nky, nkb); }
    ab ^= 1;
    // ---- step kx2: S(it+1)=A(kx0)+B in flight [9] (last triple: none) ----
    if (t < 23) asm volatile("s_waitcnt vmcnt(9)" ::: "memory");
    else        asm volatile("s_waitcnt vmcnt(0)" ::: "memory");
    __builtin_amdgcn_sched_barrier(0);
    __builtin_amdgcn_s_barrier();
    mstep(ab, bb, 2);
    __builtin_amdgcn_s_barrier();
    if (t < 23) stageA(ab, nky, 1, nkb);
    ab ^= 1;
    bb ^= 1;
  }

  // epilogue (R11-verified): D col=lane&15 (pixel), row=(lane>>4)*4+reg (o)
  const float* dB = dmod + (b << 9) + m0 + moff;
  float* op = out + (size_t)((b << 9) + m0 + moff) * 4096 + n0 + ((wv & 1) << 7);
#pragma unroll
  for (int i = 0; i < 4; ++i) {
#pragma unroll
    for (int r = 0; r < 4; ++r) {
      const int m = i * 16 + (g4 << 2) + r;
      const float dm = dB[m];
#pragma unroll
      for (int j = 0; j < 8; ++j)
        op[(size_t)m * 4096 + (j << 4) + lm] = acc[i][j][r] * dm;
    }
  }
}

extern "C" void kernel_launch(void* const* d_in, const int* in_sizes, int n_in,
                              void* d_out, int out_size, void* d_ws, size_t ws_size,
                              hipStream_t stream) {
  const float* x    = (const float*)d_in[0];   // (8,512,64,64)
  const float* w    = (const float*)d_in[1];   // (8,512)
  const float* bw   = (const float*)d_in[2];   // (1,512,512,3,3)
  const float* modw = (const float*)d_in[3];   // (512,512)
  const float* modb = (const float*)d_in[4];   // (512,)
  float* out = (float*)d_out;                  // (8,512,64,64) fp32
  char* ws = (char*)d_ws;

  float* s_buf = (float*)(ws);                              // 16 KB
  float* d_buf = (float*)(ws + 16384);                      // 16 KB
  unsigned short* awT  = (unsigned short*)(ws + 32768);     // 4,718,592 B
  unsigned short* xpad = (unsigned short*)(ws + 4751360);   // 35,684,352 B

  (void)in_sizes; (void)n_in; (void)out_size; (void)ws_size;

  k_style<<<64,   256, 0, stream>>>(w, modw, modb, s_buf);
  k_mid  <<<3104, 256, 0, stream>>>(bw, s_buf, awT, d_buf, x, xpad);
  k_conv <<<dim3(16, 2, 8), 512, 0, stream>>>(awT, xpad, d_buf, out);
}